// Round 9
// baseline (90.661 us; speedup 1.0000x reference)
//
#include <hip/hip_runtime.h>

#define GCN_N 100000
#define GCN_E 3200000
#define GCN_C 256
#define BSHIFT 8
#define NBUCK 391            // ceil(N/256)
#define BCAP 9216            // mean fill 8184, sigma ~90 -> >11 sigma headroom

#define NBP 512              // proj blocks in K1
#define NB4 1024             // hist/place chunk blocks
#define CHUNK (GCN_E / NB4)  // 3125 (exact)
#define TB 512

// K1 fused: blocks [0,NBP) = projection h = x@W (ILP x4);
// blocks [NBP,NBP+NB4) = per-chunk bucket histogram (count-only LDS atomics).
__global__ void __launch_bounds__(TB) k_proj_hist(const float* __restrict__ x,
                                                  const float* __restrict__ W,
                                                  float* __restrict__ h,
                                                  const int* __restrict__ dst,
                                                  int* __restrict__ cnts) {
    __shared__ int hist[NBUCK];
    const int tid = threadIdx.x;

    if (blockIdx.x < NBP) {
        const int lane   = tid & 63;
        const int wave   = (blockIdx.x * TB + tid) >> 6;
        const int nwaves = NBP * (TB / 64);
        const float4 wf = *reinterpret_cast<const float4*>(W + lane * 4);
        for (int i = wave * 4; i < GCN_N; i += nwaves * 4) {   // N % 4 == 0
            const float4 a0 = *reinterpret_cast<const float4*>(x + (size_t)(i + 0) * GCN_C + lane * 4);
            const float4 a1 = *reinterpret_cast<const float4*>(x + (size_t)(i + 1) * GCN_C + lane * 4);
            const float4 a2 = *reinterpret_cast<const float4*>(x + (size_t)(i + 2) * GCN_C + lane * 4);
            const float4 a3 = *reinterpret_cast<const float4*>(x + (size_t)(i + 3) * GCN_C + lane * 4);
            float s0 = a0.x * wf.x + a0.y * wf.y + a0.z * wf.z + a0.w * wf.w;
            float s1 = a1.x * wf.x + a1.y * wf.y + a1.z * wf.z + a1.w * wf.w;
            float s2 = a2.x * wf.x + a2.y * wf.y + a2.z * wf.z + a2.w * wf.w;
            float s3 = a3.x * wf.x + a3.y * wf.y + a3.z * wf.z + a3.w * wf.w;
            #pragma unroll
            for (int off = 32; off > 0; off >>= 1) {
                s0 += __shfl_down(s0, off, 64);
                s1 += __shfl_down(s1, off, 64);
                s2 += __shfl_down(s2, off, 64);
                s3 += __shfl_down(s3, off, 64);
            }
            if (lane == 0) { h[i] = s0; h[i + 1] = s1; h[i + 2] = s2; h[i + 3] = s3; }
        }
        return;
    }

    const int blk = blockIdx.x - NBP;
    for (int b = tid; b < NBUCK; b += TB) hist[b] = 0;
    __syncthreads();
    const int c0 = blk * CHUNK;
    for (int k = tid; k < CHUNK; k += TB)
        atomicAdd(&hist[dst[c0 + k] >> BSHIFT], 1);            // LDS, no-return
    __syncthreads();
    for (int b = tid; b < NBUCK; b += TB)
        cnts[(size_t)blk * NBUCK + b] = hist[b];               // coalesced row
}

// K2: per bucket b, exclusive-scan cnts[blk][b] over blk IN PLACE -> absolute
// base b*BCAP+prefix; fill[b] = min(total, BCAP).
__global__ void __launch_bounds__(1024) k_scan(int* __restrict__ cb, int* __restrict__ fill) {
    __shared__ int wsum[16], woff[16];
    const int b = blockIdx.x, tid = threadIdx.x;
    const int lane = tid & 63, w = tid >> 6;
    const int v = cb[(size_t)tid * NBUCK + b];
    int incl = v;
    #pragma unroll
    for (int d = 1; d < 64; d <<= 1) {
        const int t = __shfl_up(incl, d, 64);
        if (lane >= d) incl += t;
    }
    if (lane == 63) wsum[w] = incl;
    __syncthreads();
    if (tid == 0) { int s = 0; for (int k = 0; k < 16; ++k) { woff[k] = s; s += wsum[k]; } }
    __syncthreads();
    const int excl = incl - v + woff[w];
    cb[(size_t)tid * NBUCK + b] = b * BCAP + excl;
    if (tid == 1023) fill[b] = min(excl + v, BCAP);
}

// K3: place. LDS atomic-with-return for in-(block,bucket) offset, then DIRECT
// scattered 4B write to bpack[base+off]. No staging sort, no scan, ~3KB LDS.
__global__ void __launch_bounds__(TB) k_place(const int* __restrict__ src,
                                              const int* __restrict__ dst,
                                              const int* __restrict__ bases,
                                              int* __restrict__ bpack) {
    __shared__ int hist[NBUCK];
    __shared__ int base_s[NBUCK];
    const int tid = threadIdx.x, blk = blockIdx.x;
    for (int b = tid; b < NBUCK; b += TB) {
        hist[b]   = 0;
        base_s[b] = bases[(size_t)blk * NBUCK + b];            // coalesced row
    }
    __syncthreads();
    const int c0 = blk * CHUNK;
    for (int k = tid; k < CHUNK; k += TB) {
        const int d    = dst[c0 + k];
        const int s    = src[c0 + k];
        const int b    = d >> BSHIFT;
        const int off  = atomicAdd(&hist[b], 1);               // LDS with return
        const int gpos = base_s[b] + off;
        if (gpos < (b + 1) * BCAP)                             // overflow guard
            bpack[gpos] = (s << BSHIFT) | (d & 255);
    }
}

// K4: degree per node from bucket p; dis = rsqrt(1+deg); g = dis*h.
__global__ void __launch_bounds__(1024) k_deg_norm(const int* __restrict__ bpack,
                                                   const int* __restrict__ fill,
                                                   const float* __restrict__ h,
                                                   float* __restrict__ dis,
                                                   float* __restrict__ g) {
    __shared__ int cnt[256];
    const int p = blockIdx.x, tid = threadIdx.x;
    if (tid < 256) cnt[tid] = 0;
    __syncthreads();
    const int s0 = p * BCAP, s1 = s0 + fill[p];
    for (int i = s0 + tid; i < s1; i += 1024)
        atomicAdd(&cnt[bpack[i] & 255], 1);
    __syncthreads();
    if (tid < 256) {
        const int node = (p << BSHIFT) + tid;
        if (node < GCN_N) {
            const float r = rsqrtf(1.0f + (float)cnt[tid]);    // +1 self-loop
            dis[node] = r;
            g[node]   = r * h[node];
        }
    }
}

// K5: acc[dst&255] += g[src] over bucket p; out = b + dis*(acc + g_self).
__global__ void __launch_bounds__(1024) k_scatter_bin(const int* __restrict__ bpack,
                                                      const int* __restrict__ fill,
                                                      const float* __restrict__ g,
                                                      const float* __restrict__ dis,
                                                      const float* __restrict__ bias,
                                                      float* __restrict__ out) {
    __shared__ float acc[256];
    const int p = blockIdx.x, tid = threadIdx.x;
    if (tid < 256) acc[tid] = 0.0f;
    __syncthreads();
    const int s0 = p * BCAP, s1 = s0 + fill[p];
    for (int i = s0 + tid; i < s1; i += 1024) {
        const int pk = bpack[i];
        atomicAdd(&acc[pk & 255], g[pk >> BSHIFT]);            // LDS f32
    }
    __syncthreads();
    if (tid < 256) {
        const int node = (p << BSHIFT) + tid;
        if (node < GCN_N)
            out[node] = bias[0] + dis[node] * (acc[tid] + g[node]);
    }
}

// ---------- fallback: scattered global atomics (known-good) ----------
__global__ void k_zero(float* __restrict__ a, int n) {
    int i = blockIdx.x * blockDim.x + threadIdx.x;
    const int stride = gridDim.x * blockDim.x;
    for (; i < n; i += stride) a[i] = 0.0f;
}
__global__ void k_proj_sep(const float* __restrict__ x, const float* __restrict__ W,
                           float* __restrict__ h, int n) {
    const int lane   = threadIdx.x & 63;
    const int wave   = (blockIdx.x * blockDim.x + threadIdx.x) >> 6;
    const int nwaves = (gridDim.x * blockDim.x) >> 6;
    const float4 wf = *reinterpret_cast<const float4*>(W + lane * 4);
    for (int i = wave; i < n; i += nwaves) {
        const float4 xv = *reinterpret_cast<const float4*>(x + (size_t)i * GCN_C + lane * 4);
        float s = xv.x * wf.x + xv.y * wf.y + xv.z * wf.z + xv.w * wf.w;
        #pragma unroll
        for (int off = 32; off > 0; off >>= 1)
            s += __shfl_down(s, off, 64);
        if (lane == 0) h[i] = s;
    }
}
__global__ void k_degree_flat(const int* __restrict__ dst, float* __restrict__ deg, int e) {
    int i = blockIdx.x * blockDim.x + threadIdx.x;
    const int stride = gridDim.x * blockDim.x;
    for (; i < e; i += stride) atomicAdd(&deg[dst[i]], 1.0f);
}
__global__ void k_norm_flat(const float* __restrict__ h, float* __restrict__ deg_dis,
                            float* __restrict__ out, const float* __restrict__ bias, int n) {
    const int i = blockIdx.x * blockDim.x + threadIdx.x;
    if (i < n) {
        const float r = rsqrtf(deg_dis[i] + 1.0f);
        deg_dis[i] = r;
        out[i] = bias[0] + r * r * h[i];
    }
}
__global__ void k_scatter_flat(const int* __restrict__ src, const int* __restrict__ dst,
                               const float* __restrict__ h, const float* __restrict__ dis,
                               float* __restrict__ out, int e) {
    int i = blockIdx.x * blockDim.x + threadIdx.x;
    const int stride = gridDim.x * blockDim.x;
    for (; i < e; i += stride) {
        const int s = src[i], d = dst[i];
        atomicAdd(&out[d], dis[s] * dis[d] * h[s]);
    }
}

extern "C" void kernel_launch(void* const* d_in, const int* in_sizes, int n_in,
                              void* d_out, int out_size, void* d_ws, size_t ws_size,
                              hipStream_t stream) {
    const float* x  = (const float*)d_in[0];
    const int*   ei = (const int*)d_in[1];     // [2,E] int32: src row, dst row
    const float* W  = (const float*)d_in[2];
    const float* b  = (const float*)d_in[3];
    float* out = (float*)d_out;
    const int* src = ei;
    const int* dst = ei + GCN_E;

    float* h    = (float*)d_ws;                          // N
    float* dis  = h + GCN_N;                             // N
    float* g    = dis + GCN_N;                           // N
    int*   fill = (int*)(g + GCN_N);                     // NBUCK
    int*   cb   = fill + NBUCK;                          // NB4*NBUCK (counts -> bases)
    int*   bpack = cb + (size_t)NB4 * NBUCK;             // NBUCK*BCAP
    const size_t need = ((size_t)3 * GCN_N + NBUCK + (size_t)NB4 * NBUCK
                         + (size_t)NBUCK * BCAP) * 4;

    if (ws_size >= need) {
        k_proj_hist<<<NBP + NB4, TB, 0, stream>>>(x, W, h, dst, cb);
        k_scan<<<NBUCK, 1024, 0, stream>>>(cb, fill);
        k_place<<<NB4, TB, 0, stream>>>(src, dst, cb, bpack);
        k_deg_norm<<<NBUCK, 1024, 0, stream>>>(bpack, fill, h, dis, g);
        k_scatter_bin<<<NBUCK, 1024, 0, stream>>>(bpack, fill, g, dis, b, out);
    } else {
        float* hh  = (float*)d_ws;
        float* deg = hh + GCN_N;
        k_zero<<<512, 256, 0, stream>>>(deg, GCN_N);
        k_proj_sep<<<2048, 256, 0, stream>>>(x, W, hh, GCN_N);
        k_degree_flat<<<2048, 256, 0, stream>>>(dst, deg, GCN_E);
        k_norm_flat<<<(GCN_N + 255) / 256, 256, 0, stream>>>(hh, deg, out, b, GCN_N);
        k_scatter_flat<<<2048, 256, 0, stream>>>(src, dst, hh, deg, out, GCN_E);
    }
}

// Round 10
// 72.179 us; speedup vs baseline: 1.2561x; 1.2561x over previous
//
#include <hip/hip_runtime.h>

#define GCN_N 100000
#define GCN_E 3200000
#define GCN_C 256
#define BSHIFT 8
#define NBUCK 391            // ceil(N/256)
#define BCAP 9216            // mean fill 8184, sigma ~90 -> >11 sigma headroom

#define NPROJ 1024           // proj blocks in K1 (blockIdx 0..NPROJ-1)
#define NBIN 512             // bin blocks in K1
#define TB 512
#define CHUNK (GCN_E / NBIN) // 6250
#define EPT ((CHUNK + TB - 1) / TB)   // 13 (last iteration partially masked)

// K0: zero the cursor (must precede reservations each replay).
__global__ void k_init(int* __restrict__ cursor) {
    const int i = threadIdx.x;
    if (i < NBUCK) cursor[i] = 0;
}

// K1 fused: blocks [0,NPROJ) = proj h=x@W (ILP x4); blocks [NPROJ,NPROJ+NBIN) =
// one-pass bin: intake (LDS atomic-ret offsets, regs) -> cursor reservation
// (global atomic-ret, proven cheap) + wave-scan -> staged sort -> coalesced flush.
__global__ void __launch_bounds__(TB) k_proj_bin(const float* __restrict__ x,
                                                 const float* __restrict__ W,
                                                 float* __restrict__ h,
                                                 const int* __restrict__ src,
                                                 const int* __restrict__ dst,
                                                 int* __restrict__ cursor,
                                                 int* __restrict__ bpack) {
    __shared__ int hist[NBUCK];
    __shared__ int lscan[NBUCK];
    __shared__ int gbase[NBUCK];
    __shared__ int wsum[8], woff[8];
    __shared__ int spack[CHUNK];
    __shared__ int sdest[CHUNK];
    const int tid = threadIdx.x;

    if (blockIdx.x < NPROJ) {
        const int lane   = tid & 63;
        const int wave   = (blockIdx.x * TB + tid) >> 6;
        const int nw4    = NPROJ * (TB / 64) * 4;              // 32768 rows/round
        const float4 wf = *reinterpret_cast<const float4*>(W + lane * 4);
        for (int i = wave * 4; i < GCN_N; i += nw4) {          // N % 4 == 0
            const float4 a0 = *reinterpret_cast<const float4*>(x + (size_t)(i + 0) * GCN_C + lane * 4);
            const float4 a1 = *reinterpret_cast<const float4*>(x + (size_t)(i + 1) * GCN_C + lane * 4);
            const float4 a2 = *reinterpret_cast<const float4*>(x + (size_t)(i + 2) * GCN_C + lane * 4);
            const float4 a3 = *reinterpret_cast<const float4*>(x + (size_t)(i + 3) * GCN_C + lane * 4);
            float s0 = a0.x * wf.x + a0.y * wf.y + a0.z * wf.z + a0.w * wf.w;
            float s1 = a1.x * wf.x + a1.y * wf.y + a1.z * wf.z + a1.w * wf.w;
            float s2 = a2.x * wf.x + a2.y * wf.y + a2.z * wf.z + a2.w * wf.w;
            float s3 = a3.x * wf.x + a3.y * wf.y + a3.z * wf.z + a3.w * wf.w;
            #pragma unroll
            for (int off = 32; off > 0; off >>= 1) {
                s0 += __shfl_down(s0, off, 64);
                s1 += __shfl_down(s1, off, 64);
                s2 += __shfl_down(s2, off, 64);
                s3 += __shfl_down(s3, off, 64);
            }
            if (lane == 0) { h[i] = s0; h[i + 1] = s1; h[i + 2] = s2; h[i + 3] = s3; }
        }
        return;
    }

    // ---- binning ----
    const int blk = blockIdx.x - NPROJ;
    for (int b = tid; b < NBUCK; b += TB) hist[b] = 0;
    __syncthreads();

    // Phase 1: intake — one LDS atomic-ret per edge; everything kept in regs
    // (static unroll -> registers, not scratch).
    const int c0 = blk * CHUNK;
    int my_pack[EPT], my_b[EPT], my_off[EPT];
    #pragma unroll
    for (int j = 0; j < EPT; ++j) {
        const int k = tid + j * TB;
        my_b[j] = -1;
        if (k < CHUNK) {
            const int d = dst[c0 + k];
            const int s = src[c0 + k];
            const int b = d >> BSHIFT;
            my_pack[j] = (s << BSHIFT) | (d & 255);
            my_b[j]    = b;
            my_off[j]  = atomicAdd(&hist[b], 1);
        }
    }
    __syncthreads();

    // Phase 2: global cursor reservation (hides under scan) + wave-scan of hist.
    if (tid < NBUCK) gbase[tid] = atomicAdd(&cursor[tid], hist[tid]);
    {
        const int lane = tid & 63, w = tid >> 6;
        const int v = (tid < NBUCK) ? hist[tid] : 0;
        int incl = v;
        #pragma unroll
        for (int d2 = 1; d2 < 64; d2 <<= 1) {
            const int t = __shfl_up(incl, d2, 64);
            if (lane >= d2) incl += t;
        }
        if (lane == 63) wsum[w] = incl;
        __syncthreads();
        if (tid == 0) { int s = 0; for (int k2 = 0; k2 < 8; ++k2) { woff[k2] = s; s += wsum[k2]; } }
        __syncthreads();
        if (tid < NBUCK) lscan[tid] = incl - v + woff[w];      // exclusive
    }
    __syncthreads();

    // Phase 3: place into bucket-sorted LDS slots + global dest.
    #pragma unroll
    for (int j = 0; j < EPT; ++j) {
        if (my_b[j] >= 0) {
            const int b    = my_b[j];
            const int slot = lscan[b] + my_off[j];
            const int goff = gbase[b] + my_off[j];             // in-bucket offset
            spack[slot] = my_pack[j];
            sdest[slot] = (goff < BCAP) ? (b * BCAP + goff) : -1;  // overflow guard
        }
    }
    __syncthreads();

    // Phase 4: coalesced-run flush.
    for (int i = tid; i < CHUNK; i += TB) {
        const int dpos = sdest[i];
        if (dpos >= 0) bpack[dpos] = spack[i];
    }
}

// K2: degree per node from bucket p; dis = rsqrt(1+deg); g = dis*h.
__global__ void __launch_bounds__(1024) k_deg_norm(const int* __restrict__ bpack,
                                                   const int* __restrict__ cursor,
                                                   const float* __restrict__ h,
                                                   float* __restrict__ dis,
                                                   float* __restrict__ g) {
    __shared__ int cnt[256];
    const int p = blockIdx.x, tid = threadIdx.x;
    if (tid < 256) cnt[tid] = 0;
    __syncthreads();
    const int s0 = p * BCAP, s1 = s0 + min(cursor[p], BCAP);
    for (int i = s0 + tid; i < s1; i += 1024)
        atomicAdd(&cnt[bpack[i] & 255], 1);
    __syncthreads();
    if (tid < 256) {
        const int node = (p << BSHIFT) + tid;
        if (node < GCN_N) {
            const float r = rsqrtf(1.0f + (float)cnt[tid]);    // +1 self-loop
            dis[node] = r;
            g[node]   = r * h[node];
        }
    }
}

// K3: acc[dst&255] += g[src] over bucket p; out = b + dis*(acc + g_self).
__global__ void __launch_bounds__(1024) k_scatter_bin(const int* __restrict__ bpack,
                                                      const int* __restrict__ cursor,
                                                      const float* __restrict__ g,
                                                      const float* __restrict__ dis,
                                                      const float* __restrict__ bias,
                                                      float* __restrict__ out) {
    __shared__ float acc[256];
    const int p = blockIdx.x, tid = threadIdx.x;
    if (tid < 256) acc[tid] = 0.0f;
    __syncthreads();
    const int s0 = p * BCAP, s1 = s0 + min(cursor[p], BCAP);
    for (int i = s0 + tid; i < s1; i += 1024) {
        const int pk = bpack[i];
        atomicAdd(&acc[pk & 255], g[pk >> BSHIFT]);            // LDS f32
    }
    __syncthreads();
    if (tid < 256) {
        const int node = (p << BSHIFT) + tid;
        if (node < GCN_N)
            out[node] = bias[0] + dis[node] * (acc[tid] + g[node]);
    }
}

// ---------- fallback: scattered global atomics (known-good) ----------
__global__ void k_zero(float* __restrict__ a, int n) {
    int i = blockIdx.x * blockDim.x + threadIdx.x;
    const int stride = gridDim.x * blockDim.x;
    for (; i < n; i += stride) a[i] = 0.0f;
}
__global__ void k_proj_sep(const float* __restrict__ x, const float* __restrict__ W,
                           float* __restrict__ h, int n) {
    const int lane   = threadIdx.x & 63;
    const int wave   = (blockIdx.x * blockDim.x + threadIdx.x) >> 6;
    const int nwaves = (gridDim.x * blockDim.x) >> 6;
    const float4 wf = *reinterpret_cast<const float4*>(W + lane * 4);
    for (int i = wave; i < n; i += nwaves) {
        const float4 xv = *reinterpret_cast<const float4*>(x + (size_t)i * GCN_C + lane * 4);
        float s = xv.x * wf.x + xv.y * wf.y + xv.z * wf.z + xv.w * wf.w;
        #pragma unroll
        for (int off = 32; off > 0; off >>= 1)
            s += __shfl_down(s, off, 64);
        if (lane == 0) h[i] = s;
    }
}
__global__ void k_degree_flat(const int* __restrict__ dst, float* __restrict__ deg, int e) {
    int i = blockIdx.x * blockDim.x + threadIdx.x;
    const int stride = gridDim.x * blockDim.x;
    for (; i < e; i += stride) atomicAdd(&deg[dst[i]], 1.0f);
}
__global__ void k_norm_flat(const float* __restrict__ h, float* __restrict__ deg_dis,
                            float* __restrict__ out, const float* __restrict__ bias, int n) {
    const int i = blockIdx.x * blockDim.x + threadIdx.x;
    if (i < n) {
        const float r = rsqrtf(deg_dis[i] + 1.0f);
        deg_dis[i] = r;
        out[i] = bias[0] + r * r * h[i];
    }
}
__global__ void k_scatter_flat(const int* __restrict__ src, const int* __restrict__ dst,
                               const float* __restrict__ h, const float* __restrict__ dis,
                               float* __restrict__ out, int e) {
    int i = blockIdx.x * blockDim.x + threadIdx.x;
    const int stride = gridDim.x * blockDim.x;
    for (; i < e; i += stride) {
        const int s = src[i], d = dst[i];
        atomicAdd(&out[d], dis[s] * dis[d] * h[s]);
    }
}

extern "C" void kernel_launch(void* const* d_in, const int* in_sizes, int n_in,
                              void* d_out, int out_size, void* d_ws, size_t ws_size,
                              hipStream_t stream) {
    const float* x  = (const float*)d_in[0];
    const int*   ei = (const int*)d_in[1];     // [2,E] int32: src row, dst row
    const float* W  = (const float*)d_in[2];
    const float* b  = (const float*)d_in[3];
    float* out = (float*)d_out;
    const int* src = ei;
    const int* dst = ei + GCN_E;

    float* h      = (float*)d_ws;                        // N
    float* dis    = h + GCN_N;                           // N
    float* g      = dis + GCN_N;                         // N
    int*   cursor = (int*)(g + GCN_N);                   // NBUCK
    int*   bpack  = cursor + NBUCK;                      // NBUCK*BCAP
    const size_t need = ((size_t)3 * GCN_N + NBUCK + (size_t)NBUCK * BCAP) * 4;

    if (ws_size >= need) {
        k_init<<<1, TB, 0, stream>>>(cursor);
        k_proj_bin<<<NPROJ + NBIN, TB, 0, stream>>>(x, W, h, src, dst, cursor, bpack);
        k_deg_norm<<<NBUCK, 1024, 0, stream>>>(bpack, cursor, h, dis, g);
        k_scatter_bin<<<NBUCK, 1024, 0, stream>>>(bpack, cursor, g, dis, b, out);
    } else {
        float* hh  = (float*)d_ws;
        float* deg = hh + GCN_N;
        k_zero<<<512, 256, 0, stream>>>(deg, GCN_N);
        k_proj_sep<<<2048, 256, 0, stream>>>(x, W, hh, GCN_N);
        k_degree_flat<<<2048, 256, 0, stream>>>(dst, deg, GCN_E);
        k_norm_flat<<<(GCN_N + 255) / 256, 256, 0, stream>>>(hh, deg, out, b, GCN_N);
        k_scatter_flat<<<2048, 256, 0, stream>>>(src, dst, hh, deg, out, GCN_E);
    }
}

// Round 11
// 70.551 us; speedup vs baseline: 1.2851x; 1.0231x over previous
//
#include <hip/hip_runtime.h>

#define GCN_N 100000
#define GCN_E 3200000
#define GCN_C 256
#define BSHIFT 8
#define NBUCK 391            // ceil(N/256)
#define BCAP 9216            // mean fill 8184, sigma ~90 -> >11 sigma headroom

#define NBLK 512             // fused blocks
#define TB 1024              // threads/block
#define CHUNK (GCN_E / NBLK) // 6250 edges/block (exact)
#define EPT ((CHUNK + TB - 1) / TB)        // 7
#define ROWS ((GCN_N + NBLK - 1) / NBLK)   // 196 proj rows/block

// K0: zero cursors (re-run every replay).
__global__ void k_init(int* __restrict__ cursor) {
    const int i = threadIdx.x;
    if (i < NBUCK) cursor[i] = 0;
}

// K1: in-block fused proj + bin. Every wave first issues edge intake
// (LDS atomic-ret, latency-bound), then streams its proj rows (BW-bound);
// wave-level skew lets the CU hide intake latency under proj loads.
__global__ void __launch_bounds__(TB) k_proj_bin(const float* __restrict__ x,
                                                 const float* __restrict__ W,
                                                 float* __restrict__ h,
                                                 const int* __restrict__ src,
                                                 const int* __restrict__ dst,
                                                 int* __restrict__ cursor,
                                                 int* __restrict__ bpack) {
    __shared__ int hist[NBUCK];
    __shared__ int lscan[NBUCK];
    __shared__ int gbase[NBUCK];
    __shared__ int wsum[16], woff[16];
    __shared__ int spack[CHUNK];
    __shared__ int sdest[CHUNK];
    const int tid = threadIdx.x, blk = blockIdx.x;
    const int lane = tid & 63, wv = tid >> 6;   // 16 waves

    for (int b = tid; b < NBUCK; b += TB) hist[b] = 0;
    __syncthreads();

    // ---- Phase 1a: edge intake (one LDS atomic-ret per edge, regs only) ----
    const int c0 = blk * CHUNK;
    int my_pack[EPT], my_b[EPT], my_off[EPT];
    #pragma unroll
    for (int j = 0; j < EPT; ++j) {
        const int k = tid + j * TB;
        my_b[j] = -1;
        if (k < CHUNK) {
            const int d = dst[c0 + k];
            const int s = src[c0 + k];
            const int b = d >> BSHIFT;
            my_pack[j] = (s << BSHIFT) | (d & 255);
            my_b[j]    = b;
            my_off[j]  = atomicAdd(&hist[b], 1);
        }
    }

    // ---- Phase 1b: projection of this block's rows (1 row/wave-iter) ----
    {
        const float4 wf = *reinterpret_cast<const float4*>(W + lane * 4);
        const int r0 = blk * ROWS;
        const int r1 = min(r0 + ROWS, GCN_N);
        for (int i = r0 + wv; i < r1; i += 16) {
            const float4 xv = *reinterpret_cast<const float4*>(x + (size_t)i * GCN_C + lane * 4);
            float s = xv.x * wf.x + xv.y * wf.y + xv.z * wf.z + xv.w * wf.w;
            #pragma unroll
            for (int off = 32; off > 0; off >>= 1)
                s += __shfl_down(s, off, 64);
            if (lane == 0) h[i] = s;
        }
    }
    __syncthreads();

    // ---- Phase 2: cursor reservation + wave-scan of hist ----
    if (tid < NBUCK) gbase[tid] = atomicAdd(&cursor[tid], hist[tid]);
    {
        const int v = (tid < NBUCK) ? hist[tid] : 0;
        int incl = v;
        #pragma unroll
        for (int d2 = 1; d2 < 64; d2 <<= 1) {
            const int t = __shfl_up(incl, d2, 64);
            if (lane >= d2) incl += t;
        }
        if (lane == 63) wsum[wv] = incl;
        __syncthreads();
        if (tid == 0) { int s = 0; for (int k2 = 0; k2 < 7; ++k2) { woff[k2] = s; s += wsum[k2]; } }
        __syncthreads();
        if (tid < NBUCK) lscan[tid] = incl - v + woff[wv];     // exclusive
    }
    __syncthreads();

    // ---- Phase 3: bucket-sorted LDS staging + global dest ----
    #pragma unroll
    for (int j = 0; j < EPT; ++j) {
        if (my_b[j] >= 0) {
            const int b    = my_b[j];
            const int slot = lscan[b] + my_off[j];
            const int goff = gbase[b] + my_off[j];
            spack[slot] = my_pack[j];
            sdest[slot] = (goff < BCAP) ? (b * BCAP + goff) : -1;  // overflow guard
        }
    }
    __syncthreads();

    // ---- Phase 4: coalesced-run flush ----
    for (int i = tid; i < CHUNK; i += TB) {
        const int dpos = sdest[i];
        if (dpos >= 0) bpack[dpos] = spack[i];
    }
}

// K2: degree per node from bucket p; dis = rsqrt(1+deg); g = dis*h.
__global__ void __launch_bounds__(1024) k_deg_norm(const int* __restrict__ bpack,
                                                   const int* __restrict__ cursor,
                                                   const float* __restrict__ h,
                                                   float* __restrict__ dis,
                                                   float* __restrict__ g) {
    __shared__ int cnt[256];
    const int p = blockIdx.x, tid = threadIdx.x;
    if (tid < 256) cnt[tid] = 0;
    __syncthreads();
    const int s0 = p * BCAP, s1 = s0 + min(cursor[p], BCAP);
    for (int i = s0 + tid; i < s1; i += 1024)
        atomicAdd(&cnt[bpack[i] & 255], 1);
    __syncthreads();
    if (tid < 256) {
        const int node = (p << BSHIFT) + tid;
        if (node < GCN_N) {
            const float r = rsqrtf(1.0f + (float)cnt[tid]);    // +1 self-loop
            dis[node] = r;
            g[node]   = r * h[node];
        }
    }
}

// K3: acc[dst&255] += g[src] over bucket p; out = b + dis*(acc + g_self).
__global__ void __launch_bounds__(1024) k_scatter_bin(const int* __restrict__ bpack,
                                                      const int* __restrict__ cursor,
                                                      const float* __restrict__ g,
                                                      const float* __restrict__ dis,
                                                      const float* __restrict__ bias,
                                                      float* __restrict__ out) {
    __shared__ float acc[256];
    const int p = blockIdx.x, tid = threadIdx.x;
    if (tid < 256) acc[tid] = 0.0f;
    __syncthreads();
    const int s0 = p * BCAP, s1 = s0 + min(cursor[p], BCAP);
    for (int i = s0 + tid; i < s1; i += 1024) {
        const int pk = bpack[i];
        atomicAdd(&acc[pk & 255], g[pk >> BSHIFT]);            // LDS f32
    }
    __syncthreads();
    if (tid < 256) {
        const int node = (p << BSHIFT) + tid;
        if (node < GCN_N)
            out[node] = bias[0] + dis[node] * (acc[tid] + g[node]);
    }
}

// ---------- fallback: scattered global atomics (known-good) ----------
__global__ void k_zero(float* __restrict__ a, int n) {
    int i = blockIdx.x * blockDim.x + threadIdx.x;
    const int stride = gridDim.x * blockDim.x;
    for (; i < n; i += stride) a[i] = 0.0f;
}
__global__ void k_proj_sep(const float* __restrict__ x, const float* __restrict__ W,
                           float* __restrict__ h, int n) {
    const int lane   = threadIdx.x & 63;
    const int wave   = (blockIdx.x * blockDim.x + threadIdx.x) >> 6;
    const int nwaves = (gridDim.x * blockDim.x) >> 6;
    const float4 wf = *reinterpret_cast<const float4*>(W + lane * 4);
    for (int i = wave; i < n; i += nwaves) {
        const float4 xv = *reinterpret_cast<const float4*>(x + (size_t)i * GCN_C + lane * 4);
        float s = xv.x * wf.x + xv.y * wf.y + xv.z * wf.z + xv.w * wf.w;
        #pragma unroll
        for (int off = 32; off > 0; off >>= 1)
            s += __shfl_down(s, off, 64);
        if (lane == 0) h[i] = s;
    }
}
__global__ void k_degree_flat(const int* __restrict__ dst, float* __restrict__ deg, int e) {
    int i = blockIdx.x * blockDim.x + threadIdx.x;
    const int stride = gridDim.x * blockDim.x;
    for (; i < e; i += stride) atomicAdd(&deg[dst[i]], 1.0f);
}
__global__ void k_norm_flat(const float* __restrict__ h, float* __restrict__ deg_dis,
                            float* __restrict__ out, const float* __restrict__ bias, int n) {
    const int i = blockIdx.x * blockDim.x + threadIdx.x;
    if (i < n) {
        const float r = rsqrtf(deg_dis[i] + 1.0f);
        deg_dis[i] = r;
        out[i] = bias[0] + r * r * h[i];
    }
}
__global__ void k_scatter_flat(const int* __restrict__ src, const int* __restrict__ dst,
                               const float* __restrict__ h, const float* __restrict__ dis,
                               float* __restrict__ out, int e) {
    int i = blockIdx.x * blockDim.x + threadIdx.x;
    const int stride = gridDim.x * blockDim.x;
    for (; i < e; i += stride) {
        const int s = src[i], d = dst[i];
        atomicAdd(&out[d], dis[s] * dis[d] * h[s]);
    }
}

extern "C" void kernel_launch(void* const* d_in, const int* in_sizes, int n_in,
                              void* d_out, int out_size, void* d_ws, size_t ws_size,
                              hipStream_t stream) {
    const float* x  = (const float*)d_in[0];
    const int*   ei = (const int*)d_in[1];     // [2,E] int32: src row, dst row
    const float* W  = (const float*)d_in[2];
    const float* b  = (const float*)d_in[3];
    float* out = (float*)d_out;
    const int* src = ei;
    const int* dst = ei + GCN_E;

    float* h      = (float*)d_ws;                        // N
    float* dis    = h + GCN_N;                           // N
    float* g      = dis + GCN_N;                         // N
    int*   cursor = (int*)(g + GCN_N);                   // NBUCK
    int*   bpack  = cursor + NBUCK;                      // NBUCK*BCAP
    const size_t need = ((size_t)3 * GCN_N + NBUCK + (size_t)NBUCK * BCAP) * 4;

    if (ws_size >= need) {
        k_init<<<1, 512, 0, stream>>>(cursor);
        k_proj_bin<<<NBLK, TB, 0, stream>>>(x, W, h, src, dst, cursor, bpack);
        k_deg_norm<<<NBUCK, 1024, 0, stream>>>(bpack, cursor, h, dis, g);
        k_scatter_bin<<<NBUCK, 1024, 0, stream>>>(bpack, cursor, g, dis, b, out);
    } else {
        float* hh  = (float*)d_ws;
        float* deg = hh + GCN_N;
        k_zero<<<512, 256, 0, stream>>>(deg, GCN_N);
        k_proj_sep<<<2048, 256, 0, stream>>>(x, W, hh, GCN_N);
        k_degree_flat<<<2048, 256, 0, stream>>>(dst, deg, GCN_E);
        k_norm_flat<<<(GCN_N + 255) / 256, 256, 0, stream>>>(hh, deg, out, b, GCN_N);
        k_scatter_flat<<<2048, 256, 0, stream>>>(src, dst, hh, deg, out, GCN_E);
    }
}